// Round 1
// baseline (1841.383 us; speedup 1.0000x reference)
//
#include <hip/hip_runtime.h>

// Elman ReLU RNN, fully fused single persistent kernel.
// B=256 blocks (1 batch per CU), 256 threads (4 waves):
//   waves 0-1: h-update (j = tid < 116), W_hh row j in 116 VGPRs
//   wave  2  : fc output for h[t-1] (o = lane < 50), W_fc row o in VGPRs
//   wave  3  : xp[t+1] = W_ih x[t+1] + b_ih + b_hh (rows lane, lane+64 in VGPRs)
//              + x streaming: global -> 4-deep reg ring -> LDS ring
// One raw barrier per step (lgkmcnt-only drain; vmcnt stays in flight so the
// x prefetch pipelines across steps).

namespace {
constexpr int kB = 256;
constexpr int kT = 2048;
constexpr int kI = 50;
constexpr int kH = 116;
constexpr int kO = 50;
}

struct Smem {
  alignas(16) float h[2][128];    // h double buffer (parity t&1)
  alignas(16) float xp[2][128];   // xp double buffer (parity t&1)
  alignas(16) float xr[4][52];    // x ring, slot t&3 holds x[t] (52: pad to 13 float4)
};

__device__ __forceinline__ void sync_lds() {
  // Workgroup barrier that drains LDS only. Avoids __syncthreads()'s vmcnt(0)
  // drain, which would serialize the global x-prefetch every step.
  __asm__ __volatile__("s_waitcnt lgkmcnt(0)\n\ts_barrier" ::: "memory");
}

__device__ __forceinline__ void h_step(Smem& sm, int pw, int pr,
                                       const float (&wrow)[kH], int j) {
  const float4* hp = (const float4*)sm.h[pr];
  float a0 = sm.xp[pw][j], a1 = 0.f, a2 = 0.f, a3 = 0.f;
#pragma unroll
  for (int i = 0; i < kH / 4; ++i) {
    float4 v = hp[i];
    a0 = fmaf(wrow[4 * i + 0], v.x, a0);
    a1 = fmaf(wrow[4 * i + 1], v.y, a1);
    a2 = fmaf(wrow[4 * i + 2], v.z, a2);
    a3 = fmaf(wrow[4 * i + 3], v.w, a3);
  }
  float hn = (a0 + a1) + (a2 + a3);
  sm.h[pw][j] = hn > 0.f ? hn : 0.f;
}

__device__ __forceinline__ float fc_step(Smem& sm, int pr,
                                         const float (&wrow)[kH], float bfc) {
  const float4* hp = (const float4*)sm.h[pr];
  float a0 = bfc, a1 = 0.f, a2 = 0.f, a3 = 0.f;
#pragma unroll
  for (int i = 0; i < kH / 4; ++i) {
    float4 v = hp[i];
    a0 = fmaf(wrow[4 * i + 0], v.x, a0);
    a1 = fmaf(wrow[4 * i + 1], v.y, a1);
    a2 = fmaf(wrow[4 * i + 2], v.z, a2);
    a3 = fmaf(wrow[4 * i + 3], v.w, a3);
  }
  return (a0 + a1) + (a2 + a3);
}

__device__ __forceinline__ void xp_step(Smem& sm, int xs, int xpp,
                                        const float (&wi0)[kI],
                                        const float (&wi1)[kI],
                                        float bias0, float bias1, int ln) {
  const float4* xq = (const float4*)sm.xr[xs];
  float s00 = 0.f, s01 = 0.f, s02 = 0.f, s03 = 0.f;
  float s10 = 0.f, s11 = 0.f, s12 = 0.f, s13 = 0.f;
#pragma unroll
  for (int i = 0; i < 12; ++i) {
    float4 v = xq[i];
    s00 = fmaf(wi0[4 * i + 0], v.x, s00);
    s01 = fmaf(wi0[4 * i + 1], v.y, s01);
    s02 = fmaf(wi0[4 * i + 2], v.z, s02);
    s03 = fmaf(wi0[4 * i + 3], v.w, s03);
    s10 = fmaf(wi1[4 * i + 0], v.x, s10);
    s11 = fmaf(wi1[4 * i + 1], v.y, s11);
    s12 = fmaf(wi1[4 * i + 2], v.z, s12);
    s13 = fmaf(wi1[4 * i + 3], v.w, s13);
  }
  float2 vt = ((const float2*)sm.xr[xs])[24];  // elements 48,49
  s00 = fmaf(wi0[48], vt.x, s00);
  s01 = fmaf(wi0[49], vt.y, s01);
  s10 = fmaf(wi1[48], vt.x, s10);
  s11 = fmaf(wi1[49], vt.y, s11);
  sm.xp[xpp][ln] = bias0 + ((s00 + s01) + (s02 + s03));
  if (ln < kH - 64) sm.xp[xpp][ln + 64] = bias1 + ((s10 + s11) + (s12 + s13));
}

__launch_bounds__(256, 1)
__global__ void rnn_fused(const float* __restrict__ x,
                          const float* __restrict__ W_ih,
                          const float* __restrict__ b_ih,
                          const float* __restrict__ W_hh,
                          const float* __restrict__ b_hh,
                          const float* __restrict__ W_fc,
                          const float* __restrict__ b_fc,
                          float* __restrict__ out) {
  __shared__ Smem sm;
  const int tid = threadIdx.x;
  const int wv = tid >> 6;
  const int ln = tid & 63;
  const int b = blockIdx.x;
  const float* xb = x + (size_t)b * (kT * kI);
  float* ob = out + (size_t)b * (kT * kO);

  float wrow[kH];           // waves 0-1: W_hh row j; wave 2: W_fc row o
  float wi0[kI], wi1[kI];   // wave 3: W_ih rows ln, ln+64
  float bias0 = 0.f, bias1 = 0.f, bfc = 0.f;
  float xr0 = 0.f, xr1 = 0.f, xr2 = 0.f, xr3 = 0.f;  // x prefetch regs, by slot

  if (wv < 2) {
    if (tid < kH) {
      const float4* wr = (const float4*)(W_hh + tid * kH);  // 464B rows: 16B aligned
#pragma unroll
      for (int i = 0; i < kH / 4; ++i) {
        float4 v = wr[i];
        wrow[4 * i + 0] = v.x; wrow[4 * i + 1] = v.y;
        wrow[4 * i + 2] = v.z; wrow[4 * i + 3] = v.w;
      }
    }
  } else if (wv == 2) {
    if (ln < kO) {
      const float4* wr = (const float4*)(W_fc + ln * kH);
#pragma unroll
      for (int i = 0; i < kH / 4; ++i) {
        float4 v = wr[i];
        wrow[4 * i + 0] = v.x; wrow[4 * i + 1] = v.y;
        wrow[4 * i + 2] = v.z; wrow[4 * i + 3] = v.w;
      }
      bfc = b_fc[ln];
    }
  } else {
    {
      const float2* wr = (const float2*)(W_ih + ln * kI);  // 200B rows: 8B aligned
#pragma unroll
      for (int i = 0; i < kI / 2; ++i) {
        float2 v = wr[i]; wi0[2 * i] = v.x; wi0[2 * i + 1] = v.y;
      }
      bias0 = b_ih[ln] + b_hh[ln];
    }
    if (ln < kH - 64) {
      const float2* wr = (const float2*)(W_ih + (ln + 64) * kI);
#pragma unroll
      for (int i = 0; i < kI / 2; ++i) {
        float2 v = wr[i]; wi1[2 * i] = v.x; wi1[2 * i + 1] = v.y;
      }
      bias1 = b_ih[ln + 64] + b_hh[ln + 64];
    } else {
#pragma unroll
      for (int i = 0; i < kI; ++i) wi1[i] = 0.f;
    }
    if (ln < kI) {
      sm.xr[0][ln] = xb[0 * kI + ln];
      sm.xr[1][ln] = xb[1 * kI + ln];
      xr2 = xb[2 * kI + ln];
      xr3 = xb[3 * kI + ln];
      xr0 = xb[4 * kI + ln];
      xr1 = xb[5 * kI + ln];
    }
  }
  if (tid < 128) sm.h[1][tid] = 0.f;  // h[-1] = 0 lives at parity (0-1)&1 = 1
  sync_lds();

  if (wv == 3) xp_step(sm, /*xs=*/0, /*xpp=*/0, wi0, wi1, bias0, bias1, ln);
  sync_lds();

  // Per step t: h reads sm.xp[t&1] and sm.h[(t-1)&1], writes sm.h[t&1];
  // fc reads sm.h[(t-1)&1] -> out[t-1]; wave 3 writes sm.xp[(t+1)&1] from
  // sm.xr[(t+1)&3], refills sm.xr[(t+2)&3], prefetches x[t+6].
  // All cross-step hazards are separated by exactly the one barrier per step.
#define RNN_STEP(T_, XRV)                                                  \
  {                                                                        \
    const int t = (T_);                                                    \
    const int pw = t & 1, pr = (t + 1) & 1;                                \
    if (wv < 2) {                                                          \
      if (tid < kH) h_step(sm, pw, pr, wrow, tid);                         \
    } else if (wv == 2) {                                                  \
      if (ln < kO && t > 0) {                                              \
        float r = fc_step(sm, pr, wrow, bfc);                              \
        ob[(size_t)(t - 1) * kO + ln] = r;                                 \
      }                                                                    \
    } else {                                                               \
      xp_step(sm, (t + 1) & 3, (t + 1) & 1, wi0, wi1, bias0, bias1, ln);   \
      if (ln < kI) {                                                       \
        sm.xr[(t + 2) & 3][ln] = (XRV);                                    \
        int tf = t + 6; tf = tf < kT ? tf : kT - 1;                        \
        (XRV) = xb[(size_t)tf * kI + ln];                                  \
      }                                                                    \
    }                                                                      \
    sync_lds();                                                            \
  }

  for (int t0 = 0; t0 < kT; t0 += 4) {
    RNN_STEP(t0 + 0, xr2)
    RNN_STEP(t0 + 1, xr3)
    RNN_STEP(t0 + 2, xr0)
    RNN_STEP(t0 + 3, xr1)
  }
#undef RNN_STEP

  // fc for the final step's h (parity (T-1)&1 = 1)
  if (wv == 2 && ln < kO) {
    float r = fc_step(sm, (kT - 1) & 1, wrow, bfc);
    ob[(size_t)(kT - 1) * kO + ln] = r;
  }
}

extern "C" void kernel_launch(void* const* d_in, const int* in_sizes, int n_in,
                              void* d_out, int out_size, void* d_ws, size_t ws_size,
                              hipStream_t stream) {
  (void)in_sizes; (void)n_in; (void)d_ws; (void)ws_size; (void)out_size;
  const float* x    = (const float*)d_in[0];
  const float* W_ih = (const float*)d_in[1];
  const float* b_ih = (const float*)d_in[2];
  const float* W_hh = (const float*)d_in[3];
  const float* b_hh = (const float*)d_in[4];
  const float* W_fc = (const float*)d_in[5];
  const float* b_fc = (const float*)d_in[6];
  float* out = (float*)d_out;
  rnn_fused<<<dim3(kB), dim3(256), 0, stream>>>(x, W_ih, b_ih, W_hh, b_hh,
                                                W_fc, b_fc, out);
}